// Round 1
// baseline (592.266 us; speedup 1.0000x reference)
//
#include <hip/hip_runtime.h>

#define BH 64            // B*H heads
#define SEQ 8192
#define DK 128
#define DV 128
#define NCHUNK 8         // S-chunks per head -> 512 blocks
#define SC (SEQ / NCHUNK)  // 1024 s-rows per block
#define CS 64            // s-rows per LDS stage
#define NSTAGE (SC / CS) // 16
#define LR 72            // LDS row pitch in f16 (144 B: 16B-aligned rows, odd/2 bank coef)

typedef _Float16 f16;
typedef _Float16 f16x4 __attribute__((ext_vector_type(4)));
typedef _Float16 f16x8 __attribute__((ext_vector_type(8)));
typedef float f32x4 __attribute__((ext_vector_type(4)));

// Phase 1: per (head, s-chunk) block, accumulate P = phi^T V into newM (pre-init = M),
// G = phi^T phi into workspace, colsum(phi) into newZ (pre-init = z).
__global__ __launch_bounds__(256, 2) void delta_phase1(
    const float* __restrict__ Kg, const float* __restrict__ Vg,
    float* __restrict__ newM, float* __restrict__ newZ, float* __restrict__ Gws)
{
  __shared__ f16 phi_lds[DK * LR];  // [feat][s] transposed, f16
  __shared__ f16 v_lds[DV * LR];

  const int bh    = blockIdx.x >> 3;
  const int chunk = blockIdx.x & 7;
  const int tid   = threadIdx.x;
  const int wave  = tid >> 6;
  const int lane  = tid & 63;
  const int l31   = lane & 31;
  const int lhi   = lane >> 5;   // 0/1
  const int f15_  = lane & 15;   // MFMA frag row/col
  const int quad  = lane >> 4;   // 0..3

  const float* Kh = Kg + ((size_t)bh * SEQ + (size_t)chunk * SC) * DK;
  const float* Vh = Vg + ((size_t)bh * SEQ + (size_t)chunk * SC) * DV;

  f32x4 acc[8][4];   // 8 row-tiles x 4 col-tiles of 16x16 (wave owns 64 output cols)
#pragma unroll
  for (int r = 0; r < 8; ++r)
#pragma unroll
    for (int c = 0; c < 4; ++c)
      acc[r][c] = (f32x4){0.f, 0.f, 0.f, 0.f};

  float zacc[4] = {0.f, 0.f, 0.f, 0.f};  // colsum partials, feat = fj*32 + l31

  for (int st = 0; st < NSTAGE; ++st) {
    __syncthreads();  // previous stage's LDS reads done before overwrite
    const float* Ks = Kh + (size_t)st * CS * DK;
    const float* Vs = Vh + (size_t)st * CS * DV;
    // Staging: wave w loads s-rows [16w,16w+16). Lane: fixed feat, 4 consecutive s
    // (global: 32 lanes x 4B = 128B contiguous per row segment; LDS: 8B transposed store).
#pragma unroll
    for (int fj = 0; fj < 4; ++fj) {
      const int feat = fj * 32 + l31;
#pragma unroll
      for (int sq = 0; sq < 2; ++sq) {
        const int srow = wave * 16 + sq * 8 + lhi * 4;
        const float* kp = Ks + (size_t)srow * DK + feat;
        const float a0 = kp[0];
        const float a1 = kp[DK];
        const float a2 = kp[2 * DK];
        const float a3 = kp[3 * DK];
        const float p0 = a0 > 0.f ? a0 + 1.f : __expf(a0);  // elu(x)+1
        const float p1 = a1 > 0.f ? a1 + 1.f : __expf(a1);
        const float p2 = a2 > 0.f ? a2 + 1.f : __expf(a2);
        const float p3 = a3 > 0.f ? a3 + 1.f : __expf(a3);
        zacc[fj] += (p0 + p1) + (p2 + p3);
        *(f16x4*)&phi_lds[feat * LR + srow] =
            (f16x4){(f16)p0, (f16)p1, (f16)p2, (f16)p3};
        const float* vp = Vs + (size_t)srow * DV + feat;
        *(f16x4*)&v_lds[feat * LR + srow] =
            (f16x4){(f16)vp[0], (f16)vp[DV], (f16)vp[2 * DV], (f16)vp[3 * DV]};
      }
    }
    __syncthreads();
    // Compute: 2 K-steps of 32 over s. Wave w owns output cols [64w, 64w+64):
    // cols 0..127 -> phi^T V, cols 128..255 -> phi^T phi.
#pragma unroll
    for (int ss = 0; ss < 2; ++ss) {
      const int sb = ss * 32 + quad * 8;
      f16x8 bfr[4];
#pragma unroll
      for (int c = 0; c < 4; ++c) {
        const int col = wave * 64 + c * 16;
        const f16* wsrc = (col < DV) ? &v_lds[(col + f15_) * LR]
                                     : &phi_lds[(col - DV + f15_) * LR];
        bfr[c] = *(const f16x8*)&wsrc[sb];
      }
#pragma unroll
      for (int r = 0; r < 8; ++r) {
        const f16x8 afr = *(const f16x8*)&phi_lds[(r * 16 + f15_) * LR + sb];
#pragma unroll
        for (int c = 0; c < 4; ++c)
          acc[r][c] = __builtin_amdgcn_mfma_f32_16x16x32_f16(afr, bfr[c], acc[r][c], 0, 0, 0);
      }
    }
  }

  // Epilogue: C/D layout col=lane&15, row=quad*4+reg
  const size_t mb = (size_t)bh * DK * DV;
#pragma unroll
  for (int r = 0; r < 8; ++r) {
#pragma unroll
    for (int c = 0; c < 4; ++c) {
      const int col = wave * 64 + c * 16 + f15_;
#pragma unroll
      for (int q = 0; q < 4; ++q) {
        const int row = r * 16 + quad * 4 + q;
        const float v = acc[r][c][q];
        if (col < DV)
          atomicAdd(&newM[mb + (size_t)row * DV + col], v);
        else
          atomicAdd(&Gws[mb + (size_t)row * DK + (col - DV)], v);
      }
    }
  }
  // z: lanes l and l+32 share feat -> shfl reduce, then one atomic per feat per wave
#pragma unroll
  for (int fj = 0; fj < 4; ++fj) {
    float v = zacc[fj];
    v += __shfl_xor(v, 32, 64);
    if (lhi == 0) atomicAdd(&newZ[bh * DK + fj * 32 + l31], v);
  }
}

// Phase 2: newM -= G * M (per head, fp32). Grid = BH*8: kh half x 4 v-tiles.
__global__ __launch_bounds__(256) void delta_phase2(
    const float* __restrict__ Mg, const float* __restrict__ Gws, float* __restrict__ newM)
{
  __shared__ float Gs[64 * 129];  // 64 k-rows of G, padded (bank spread)
  __shared__ float Ms[DK * 32];   // 32-col tile of M
  const int bh  = blockIdx.x >> 3;
  const int sub = blockIdx.x & 7;
  const int kh  = sub >> 2;   // k half
  const int vt  = sub & 3;    // v tile
  const int tid = threadIdx.x;
  const size_t mb = (size_t)bh * DK * DV;

  for (int i = tid; i < 64 * DK; i += 256)
    Gs[(i >> 7) * 129 + (i & 127)] = Gws[mb + (size_t)(kh * 64 + (i >> 7)) * DK + (i & 127)];
  for (int i = tid; i < DK * 32; i += 256)
    Ms[i] = Mg[mb + (size_t)(i >> 5) * DV + vt * 32 + (i & 31)];
  __syncthreads();

  const int kl = tid >> 2;         // 0..63
  const int vs = (tid & 3) * 8;    // 0..24
  float a[8];
#pragma unroll
  for (int j = 0; j < 8; ++j) a[j] = 0.f;
  for (int kk = 0; kk < DK; ++kk) {
    const float g = Gs[kl * 129 + kk];
#pragma unroll
    for (int j = 0; j < 8; ++j) a[j] += g * Ms[kk * 32 + vs + j];
  }
  float* dst = &newM[mb + (size_t)(kh * 64 + kl) * DV + vt * 32 + vs];
#pragma unroll
  for (int j = 0; j < 8; ++j) dst[j] -= a[j];
}

extern "C" void kernel_launch(void* const* d_in, const int* in_sizes, int n_in,
                              void* d_out, int out_size, void* d_ws, size_t ws_size,
                              hipStream_t stream) {
  const float* Kg = (const float*)d_in[0];
  const float* Vg = (const float*)d_in[1];
  const float* Mg = (const float*)d_in[2];
  const float* zg = (const float*)d_in[3];
  float* out  = (float*)d_out;
  float* newM = out;                              // BH*DK*DV floats
  float* newZ = out + (size_t)BH * DK * DV;       // BH*DK floats
  float* Gws  = (float*)d_ws;                     // BH*DK*DK floats (4.2 MB)

  hipMemcpyAsync(newM, Mg, sizeof(float) * (size_t)BH * DK * DV,
                 hipMemcpyDeviceToDevice, stream);
  hipMemcpyAsync(newZ, zg, sizeof(float) * (size_t)BH * DK,
                 hipMemcpyDeviceToDevice, stream);
  hipMemsetAsync(Gws, 0, sizeof(float) * (size_t)BH * DK * DK, stream);

  delta_phase1<<<dim3(BH * NCHUNK), dim3(256), 0, stream>>>(Kg, Vg, newM, newZ, Gws);
  delta_phase2<<<dim3(BH * 8), dim3(256), 0, stream>>>(Mg, Gws, newM);
}

// Round 2
// 587.915 us; speedup vs baseline: 1.0074x; 1.0074x over previous
//
#include <hip/hip_runtime.h>

#define BH 64            // B*H heads
#define SEQ 8192
#define DK 128
#define DV 128
#define CS 64            // s-rows per LDS stage
#define LR 72            // LDS row pitch in f16 (144 B: 16B-aligned rows)

typedef _Float16 f16;
typedef _Float16 f16x4 __attribute__((ext_vector_type(4)));
typedef _Float16 f16x8 __attribute__((ext_vector_type(8)));
typedef float f32x4 __attribute__((ext_vector_type(4)));

// Phase 1: per (head, s-chunk) block of 512 threads (8 waves). Each wave owns 32
// of the 256 output cols (cols 0..127 = phi^T V, 128..255 = phi^T phi), so the
// accumulator is only 64 f32/lane -> fits 2 blocks/CU (16 waves) at <=128 regs.
// PARTIAL: store per-chunk partials to ws (no atomics). else: atomicAdd (fallback).
template <int NC, bool PARTIAL>
__global__ __launch_bounds__(512, 4) void delta_phase1(
    const float* __restrict__ Kg, const float* __restrict__ Vg,
    float* __restrict__ dstP,   // PARTIAL: ws partial base ; atomic: newM
    float* __restrict__ dstG,   // PARTIAL: unused         ; atomic: Gws
    float* __restrict__ newZ)
{
  __shared__ f16 phi_lds[DK * LR];  // [feat][s] transposed, f16
  __shared__ f16 v_lds[DV * LR];

  constexpr int SC  = SEQ / NC;   // s-rows per block
  constexpr int NST = SC / CS;    // stages

  const int chunk = blockIdx.x;
  const int bh    = blockIdx.y;
  const int tid   = threadIdx.x;
  const int wave  = tid >> 6;    // 0..7
  const int lane  = tid & 63;
  const int l31   = lane & 31;
  const int lhi   = lane >> 5;   // 0/1
  const int f15_  = lane & 15;
  const int quad  = lane >> 4;   // 0..3

  const float* Kh = Kg + ((size_t)bh * SEQ + (size_t)chunk * SC) * DK;
  const float* Vh = Vg + ((size_t)bh * SEQ + (size_t)chunk * SC) * DV;

  f32x4 acc[8][2];   // 8 row-tiles x 2 col-tiles of 16x16 (wave owns 32 cols)
#pragma unroll
  for (int r = 0; r < 8; ++r)
#pragma unroll
    for (int c = 0; c < 2; ++c)
      acc[r][c] = (f32x4){0.f, 0.f, 0.f, 0.f};

  float zacc[4] = {0.f, 0.f, 0.f, 0.f};  // colsum partials, feat = fj*32 + l31

  for (int st = 0; st < NST; ++st) {
    __syncthreads();  // previous stage's LDS reads done before overwrite
    const float* Ks = Kh + (size_t)st * CS * DK;
    const float* Vs = Vh + (size_t)st * CS * DV;
    // Staging: wave w loads s-rows [8w, 8w+8). Lane: fixed feat, 4 consecutive s.
    const int srow = wave * 8 + lhi * 4;
#pragma unroll
    for (int fj = 0; fj < 4; ++fj) {
      const int feat = fj * 32 + l31;
      const float* kp = Ks + (size_t)srow * DK + feat;
      const float a0 = kp[0];
      const float a1 = kp[DK];
      const float a2 = kp[2 * DK];
      const float a3 = kp[3 * DK];
      const float p0 = a0 > 0.f ? a0 + 1.f : __expf(a0);  // elu(x)+1
      const float p1 = a1 > 0.f ? a1 + 1.f : __expf(a1);
      const float p2 = a2 > 0.f ? a2 + 1.f : __expf(a2);
      const float p3 = a3 > 0.f ? a3 + 1.f : __expf(a3);
      zacc[fj] += (p0 + p1) + (p2 + p3);
      *(f16x4*)&phi_lds[feat * LR + srow] =
          (f16x4){(f16)p0, (f16)p1, (f16)p2, (f16)p3};
      const float* vp = Vs + (size_t)srow * DV + feat;
      *(f16x4*)&v_lds[feat * LR + srow] =
          (f16x4){(f16)vp[0], (f16)vp[DV], (f16)vp[2 * DV], (f16)vp[3 * DV]};
    }
    __syncthreads();
    // Compute: 2 K-steps of 32 over s.
    const f16* bsrc  = (wave < 4) ? v_lds : phi_lds;
    const int  cbase = (wave < 4) ? wave * 32 : wave * 32 - 128;
#pragma unroll
    for (int ss = 0; ss < 2; ++ss) {
      const int sb = ss * 32 + quad * 8;
      f16x8 bfr[2];
#pragma unroll
      for (int c = 0; c < 2; ++c)
        bfr[c] = *(const f16x8*)&bsrc[(cbase + c * 16 + f15_) * LR + sb];
#pragma unroll
      for (int r = 0; r < 8; ++r) {
        const f16x8 afr = *(const f16x8*)&phi_lds[(r * 16 + f15_) * LR + sb];
        acc[r][0] = __builtin_amdgcn_mfma_f32_16x16x32_f16(afr, bfr[0], acc[r][0], 0, 0, 0);
        acc[r][1] = __builtin_amdgcn_mfma_f32_16x16x32_f16(afr, bfr[1], acc[r][1], 0, 0, 0);
      }
    }
  }

  // Epilogue: C/D layout col=lane&15, row=quad*4+reg
  if (PARTIAL) {
    const size_t pb = (size_t)(bh * NC + chunk) * (128 * 256);
#pragma unroll
    for (int r = 0; r < 8; ++r)
#pragma unroll
      for (int c = 0; c < 2; ++c) {
        const int col = wave * 32 + c * 16 + f15_;
#pragma unroll
        for (int q = 0; q < 4; ++q) {
          const int row = r * 16 + quad * 4 + q;
          dstP[pb + (size_t)row * 256 + col] = acc[r][c][q];
        }
      }
  } else {
    const size_t mb = (size_t)bh * DK * DV;
#pragma unroll
    for (int r = 0; r < 8; ++r)
#pragma unroll
      for (int c = 0; c < 2; ++c) {
        const int col = wave * 32 + c * 16 + f15_;
#pragma unroll
        for (int q = 0; q < 4; ++q) {
          const int row = r * 16 + quad * 4 + q;
          const float v = acc[r][c][q];
          if (col < DV)
            atomicAdd(&dstP[mb + (size_t)row * DV + col], v);
          else
            atomicAdd(&dstG[mb + (size_t)row * DK + (col - DV)], v);
        }
      }
  }
  // z: lanes l and l+32 share feat -> shfl reduce, one atomic per feat per wave
#pragma unroll
  for (int fj = 0; fj < 4; ++fj) {
    float v = zacc[fj];
    v += __shfl_xor(v, 32, 64);
    if (lhi == 0) atomicAdd(&newZ[bh * DK + fj * 32 + l31], v);
  }
}

// Reduce per-chunk partials: newM(cols<128) = M + sum, Gred(cols>=128) = sum.
__global__ __launch_bounds__(256) void delta_reduce(
    const float* __restrict__ Pp, const float* __restrict__ Mg,
    float* __restrict__ newM, float* __restrict__ Gred, int NC)
{
  const int ct  = blockIdx.x;       // 0..7 -> 32-col tile
  const int bh  = blockIdx.y;
  const int tid = threadIdx.x;
  const int col = ct * 32 + (tid & 31);
  const int r0  = tid >> 5;         // 0..7

  float acc[16];
#pragma unroll
  for (int i = 0; i < 16; ++i) acc[i] = 0.f;

  const float* base = Pp + (size_t)(bh * NC) * 32768;
  for (int ch = 0; ch < NC; ++ch) {
    const float* p = base + (size_t)ch * 32768;
#pragma unroll
    for (int i = 0; i < 16; ++i)
      acc[i] += p[(size_t)(r0 + 8 * i) * 256 + col];
  }
  if (col < 128) {
#pragma unroll
    for (int i = 0; i < 16; ++i) {
      const int row = r0 + 8 * i;
      newM[(size_t)bh * 16384 + (size_t)row * 128 + col] =
          Mg[(size_t)bh * 16384 + (size_t)row * 128 + col] + acc[i];
    }
  } else {
#pragma unroll
    for (int i = 0; i < 16; ++i) {
      const int row = r0 + 8 * i;
      Gred[(size_t)bh * 16384 + (size_t)row * 128 + (col - 128)] = acc[i];
    }
  }
}

// newM -= G * M (per head, fp32).
__global__ __launch_bounds__(256) void delta_gm(
    const float* __restrict__ Mg, const float* __restrict__ G, float* __restrict__ newM)
{
  __shared__ float Gs[64 * 129];
  __shared__ float Ms[DK * 32];
  const int sub = blockIdx.x;  // 0..7
  const int bh  = blockIdx.y;
  const int kh  = sub >> 2;    // k half
  const int vt  = sub & 3;     // v tile
  const int tid = threadIdx.x;
  const size_t mb = (size_t)bh * DK * DV;

  for (int i = tid; i < 64 * DK; i += 256)
    Gs[(i >> 7) * 129 + (i & 127)] = G[mb + (size_t)(kh * 64 + (i >> 7)) * DK + (i & 127)];
  for (int i = tid; i < DK * 32; i += 256)
    Ms[i] = Mg[mb + (size_t)(i >> 5) * DV + vt * 32 + (i & 31)];
  __syncthreads();

  const int kl = tid >> 2;
  const int vs = (tid & 3) * 8;
  float a[8];
#pragma unroll
  for (int j = 0; j < 8; ++j) a[j] = 0.f;
  for (int kk = 0; kk < DK; ++kk) {
    const float g = Gs[kl * 129 + kk];
#pragma unroll
    for (int j = 0; j < 8; ++j) a[j] += g * Ms[kk * 32 + vs + j];
  }
  float* dst = &newM[mb + (size_t)(kh * 64 + kl) * DV + vt * 32 + vs];
#pragma unroll
  for (int j = 0; j < 8; ++j) dst[j] -= a[j];
}

extern "C" void kernel_launch(void* const* d_in, const int* in_sizes, int n_in,
                              void* d_out, int out_size, void* d_ws, size_t ws_size,
                              hipStream_t stream) {
  const float* Kg = (const float*)d_in[0];
  const float* Vg = (const float*)d_in[1];
  const float* Mg = (const float*)d_in[2];
  const float* zg = (const float*)d_in[3];
  float* out  = (float*)d_out;
  float* newM = out;                              // BH*DK*DV floats
  float* newZ = out + (size_t)BH * DK * DV;       // BH*DK floats

  const size_t gredF = (size_t)BH * DK * DK;      // 1M floats (4 MB)
  const size_t need16 = ((size_t)BH * 16 * 32768 + gredF) * sizeof(float);  // ~138 MB
  const size_t need8  = ((size_t)BH * 8  * 32768 + gredF) * sizeof(float);  // ~71 MB

  hipMemcpyAsync(newZ, zg, sizeof(float) * (size_t)BH * DK,
                 hipMemcpyDeviceToDevice, stream);

  if (ws_size >= need16) {
    float* Pp   = (float*)d_ws;
    float* Gred = Pp + (size_t)BH * 16 * 32768;
    delta_phase1<16, true><<<dim3(16, BH), 512, 0, stream>>>(Kg, Vg, Pp, nullptr, newZ);
    delta_reduce<<<dim3(8, BH), 256, 0, stream>>>(Pp, Mg, newM, Gred, 16);
    delta_gm<<<dim3(8, BH), 256, 0, stream>>>(Mg, Gred, newM);
  } else if (ws_size >= need8) {
    float* Pp   = (float*)d_ws;
    float* Gred = Pp + (size_t)BH * 8 * 32768;
    delta_phase1<8, true><<<dim3(8, BH), 512, 0, stream>>>(Kg, Vg, Pp, nullptr, newZ);
    delta_reduce<<<dim3(8, BH), 256, 0, stream>>>(Pp, Mg, newM, Gred, 8);
    delta_gm<<<dim3(8, BH), 256, 0, stream>>>(Mg, Gred, newM);
  } else {
    // Atomic fallback: newM/Gws pre-initialized, phase1 accumulates in place.
    float* Gws = (float*)d_ws;                    // 4 MB
    hipMemcpyAsync(newM, Mg, sizeof(float) * (size_t)BH * DK * DV,
                   hipMemcpyDeviceToDevice, stream);
    hipMemsetAsync(Gws, 0, sizeof(float) * gredF, stream);
    delta_phase1<16, false><<<dim3(16, BH), 512, 0, stream>>>(Kg, Vg, newM, Gws, newZ);
    delta_gm<<<dim3(8, BH), 256, 0, stream>>>(Mg, Gws, newM);
  }
}

// Round 3
// 565.192 us; speedup vs baseline: 1.0479x; 1.0402x over previous
//
#include <hip/hip_runtime.h>

#define BH 64            // B*H heads
#define SEQ 8192
#define DK 128
#define DV 128
#define CS 64            // s-rows per LDS stage
#define LR 72            // LDS row pitch in f16 (144 B: 16B-aligned rows)

typedef _Float16 f16;
typedef _Float16 f16x4 __attribute__((ext_vector_type(4)));
typedef _Float16 f16x8 __attribute__((ext_vector_type(8)));
typedef float f32x4 __attribute__((ext_vector_type(4)));

// Phase 1: per (head, s-chunk) block of 512 threads (8 waves). Each wave owns 32
// of the 256 output cols (0..127 = phi^T V, 128..255 = phi^T phi).
// Software-pipelined: stage t+1's global loads are issued into registers before
// stage t's MFMA phase, so HBM latency overlaps compute instead of stalling it.
template <int NC, bool PARTIAL>
__global__ __launch_bounds__(512, 4) void delta_phase1(
    const float* __restrict__ Kg, const float* __restrict__ Vg,
    float* __restrict__ dstP,   // PARTIAL: ws partial base ; atomic: newM
    float* __restrict__ dstG,   // PARTIAL: unused         ; atomic: Gws
    float* __restrict__ newZ)
{
  __shared__ f16 phi_lds[DK * LR];  // [feat][s] transposed, f16
  __shared__ f16 v_lds[DV * LR];

  constexpr int SC  = SEQ / NC;   // s-rows per block
  constexpr int NST = SC / CS;    // stages

  const int chunk = blockIdx.x;
  const int bh    = blockIdx.y;
  const int tid   = threadIdx.x;
  const int wave  = tid >> 6;    // 0..7
  const int lane  = tid & 63;
  const int l31   = lane & 31;
  const int lhi   = lane >> 5;   // 0/1
  const int f15_  = lane & 15;
  const int quad  = lane >> 4;   // 0..3

  const float* Kh = Kg + ((size_t)bh * SEQ + (size_t)chunk * SC) * DK;
  const float* Vh = Vg + ((size_t)bh * SEQ + (size_t)chunk * SC) * DV;
  const int srow = wave * 8 + lhi * 4;   // this thread's s-row base within a stage

  f32x4 acc[8][2];   // 8 row-tiles x 2 col-tiles of 16x16 (wave owns 32 cols)
#pragma unroll
  for (int r = 0; r < 8; ++r)
#pragma unroll
    for (int c = 0; c < 2; ++c)
      acc[r][c] = (f32x4){0.f, 0.f, 0.f, 0.f};

  float zacc[4] = {0.f, 0.f, 0.f, 0.f};  // colsum partials, feat = fj*32 + l31

  float kr[16], vr[16];   // prefetch registers for one stage
#define LOAD_STAGE(ST)                                              \
  {                                                                 \
    const float* Ks_ = Kh + (size_t)(ST) * CS * DK;                 \
    const float* Vs_ = Vh + (size_t)(ST) * CS * DV;                 \
    _Pragma("unroll")                                               \
    for (int fj = 0; fj < 4; ++fj) {                                \
      const int feat_ = fj * 32 + l31;                              \
      const float* kp_ = Ks_ + (size_t)srow * DK + feat_;           \
      const float* vp_ = Vs_ + (size_t)srow * DV + feat_;           \
      _Pragma("unroll")                                             \
      for (int j = 0; j < 4; ++j) {                                 \
        kr[fj * 4 + j] = kp_[(size_t)j * DK];                       \
        vr[fj * 4 + j] = vp_[(size_t)j * DV];                       \
      }                                                             \
    }                                                               \
  }

  LOAD_STAGE(0);

  for (int st = 0; st < NST; ++st) {
    // Convert + transposed LDS store (consumes prefetch regs of stage st).
#pragma unroll
    for (int fj = 0; fj < 4; ++fj) {
      const int feat = fj * 32 + l31;
      const float a0 = kr[fj * 4 + 0];
      const float a1 = kr[fj * 4 + 1];
      const float a2 = kr[fj * 4 + 2];
      const float a3 = kr[fj * 4 + 3];
      const float p0 = a0 > 0.f ? a0 + 1.f : __expf(a0);  // elu(x)+1
      const float p1 = a1 > 0.f ? a1 + 1.f : __expf(a1);
      const float p2 = a2 > 0.f ? a2 + 1.f : __expf(a2);
      const float p3 = a3 > 0.f ? a3 + 1.f : __expf(a3);
      zacc[fj] += (p0 + p1) + (p2 + p3);
      *(f16x4*)&phi_lds[feat * LR + srow] =
          (f16x4){(f16)p0, (f16)p1, (f16)p2, (f16)p3};
      *(f16x4*)&v_lds[feat * LR + srow] =
          (f16x4){(f16)vr[fj * 4 + 0], (f16)vr[fj * 4 + 1],
                  (f16)vr[fj * 4 + 2], (f16)vr[fj * 4 + 3]};
    }
    __syncthreads();

    // Issue next stage's loads NOW; results not consumed until after the
    // trailing barrier -> latency hides behind the MFMA phase below.
    if (st + 1 < NST) LOAD_STAGE(st + 1);

    // Compute: 2 K-steps of 32 over s.
    const f16* bsrc  = (wave < 4) ? v_lds : phi_lds;
    const int  cbase = (wave < 4) ? wave * 32 : wave * 32 - 128;
#pragma unroll
    for (int ss = 0; ss < 2; ++ss) {
      const int sb = ss * 32 + quad * 8;
      f16x8 bfr[2];
#pragma unroll
      for (int c = 0; c < 2; ++c)
        bfr[c] = *(const f16x8*)&bsrc[(cbase + c * 16 + f15_) * LR + sb];
#pragma unroll
      for (int r = 0; r < 8; ++r) {
        const f16x8 afr = *(const f16x8*)&phi_lds[(r * 16 + f15_) * LR + sb];
        acc[r][0] = __builtin_amdgcn_mfma_f32_16x16x32_f16(afr, bfr[0], acc[r][0], 0, 0, 0);
        acc[r][1] = __builtin_amdgcn_mfma_f32_16x16x32_f16(afr, bfr[1], acc[r][1], 0, 0, 0);
      }
    }
    __syncthreads();  // LDS reads done before next stage's convert overwrites
  }
#undef LOAD_STAGE

  // Epilogue: C/D layout col=lane&15, row=quad*4+reg
  if (PARTIAL) {
    const size_t pb = (size_t)(bh * NC + chunk) * (128 * 256);
#pragma unroll
    for (int r = 0; r < 8; ++r)
#pragma unroll
      for (int c = 0; c < 2; ++c) {
        const int col = wave * 32 + c * 16 + f15_;
#pragma unroll
        for (int q = 0; q < 4; ++q) {
          const int row = r * 16 + quad * 4 + q;
          dstP[pb + (size_t)row * 256 + col] = acc[r][c][q];
        }
      }
  } else {
    const size_t mb = (size_t)bh * DK * DV;
#pragma unroll
    for (int r = 0; r < 8; ++r)
#pragma unroll
      for (int c = 0; c < 2; ++c) {
        const int col = wave * 32 + c * 16 + f15_;
#pragma unroll
        for (int q = 0; q < 4; ++q) {
          const int row = r * 16 + quad * 4 + q;
          const float v = acc[r][c][q];
          if (col < DV)
            atomicAdd(&dstP[mb + (size_t)row * DV + col], v);
          else
            atomicAdd(&dstG[mb + (size_t)row * DK + (col - DV)], v);
        }
      }
  }
  // z: lanes l and l+32 share feat -> shfl reduce, one atomic per feat per wave
#pragma unroll
  for (int fj = 0; fj < 4; ++fj) {
    float v = zacc[fj];
    v += __shfl_xor(v, 32, 64);
    if (lhi == 0) atomicAdd(&newZ[bh * DK + fj * 32 + l31], v);
  }
}

// Reduce per-chunk partials: newM(cols<128) = M + sum, Gred(cols>=128) = sum.
__global__ __launch_bounds__(256) void delta_reduce(
    const float* __restrict__ Pp, const float* __restrict__ Mg,
    float* __restrict__ newM, float* __restrict__ Gred, int NC)
{
  const int ct  = blockIdx.x;       // 0..7 -> 32-col tile
  const int bh  = blockIdx.y;
  const int tid = threadIdx.x;
  const int col = ct * 32 + (tid & 31);
  const int r0  = tid >> 5;         // 0..7

  float acc[16];
#pragma unroll
  for (int i = 0; i < 16; ++i) acc[i] = 0.f;

  const float* base = Pp + (size_t)(bh * NC) * 32768;
  for (int ch = 0; ch < NC; ++ch) {
    const float* p = base + (size_t)ch * 32768;
#pragma unroll
    for (int i = 0; i < 16; ++i)
      acc[i] += p[(size_t)(r0 + 8 * i) * 256 + col];
  }
  if (col < 128) {
#pragma unroll
    for (int i = 0; i < 16; ++i) {
      const int row = r0 + 8 * i;
      newM[(size_t)bh * 16384 + (size_t)row * 128 + col] =
          Mg[(size_t)bh * 16384 + (size_t)row * 128 + col] + acc[i];
    }
  } else {
#pragma unroll
    for (int i = 0; i < 16; ++i) {
      const int row = r0 + 8 * i;
      Gred[(size_t)bh * 16384 + (size_t)row * 128 + (col - 128)] = acc[i];
    }
  }
}

// newM -= G * M (per head, fp32).
__global__ __launch_bounds__(256) void delta_gm(
    const float* __restrict__ Mg, const float* __restrict__ G, float* __restrict__ newM)
{
  __shared__ float Gs[64 * 129];
  __shared__ float Ms[DK * 32];
  const int sub = blockIdx.x;  // 0..7
  const int bh  = blockIdx.y;
  const int kh  = sub >> 2;    // k half
  const int vt  = sub & 3;     // v tile
  const int tid = threadIdx.x;
  const size_t mb = (size_t)bh * DK * DV;

  for (int i = tid; i < 64 * DK; i += 256)
    Gs[(i >> 7) * 129 + (i & 127)] = G[mb + (size_t)(kh * 64 + (i >> 7)) * DK + (i & 127)];
  for (int i = tid; i < DK * 32; i += 256)
    Ms[i] = Mg[mb + (size_t)(i >> 5) * DV + vt * 32 + (i & 31)];
  __syncthreads();

  const int kl = tid >> 2;
  const int vs = (tid & 3) * 8;
  float a[8];
#pragma unroll
  for (int j = 0; j < 8; ++j) a[j] = 0.f;
  for (int kk = 0; kk < DK; ++kk) {
    const float g = Gs[kl * 129 + kk];
#pragma unroll
    for (int j = 0; j < 8; ++j) a[j] += g * Ms[kk * 32 + vs + j];
  }
  float* dst = &newM[mb + (size_t)(kh * 64 + kl) * DV + vt * 32 + vs];
#pragma unroll
  for (int j = 0; j < 8; ++j) dst[j] -= a[j];
}

extern "C" void kernel_launch(void* const* d_in, const int* in_sizes, int n_in,
                              void* d_out, int out_size, void* d_ws, size_t ws_size,
                              hipStream_t stream) {
  const float* Kg = (const float*)d_in[0];
  const float* Vg = (const float*)d_in[1];
  const float* Mg = (const float*)d_in[2];
  const float* zg = (const float*)d_in[3];
  float* out  = (float*)d_out;
  float* newM = out;                              // BH*DK*DV floats
  float* newZ = out + (size_t)BH * DK * DV;       // BH*DK floats

  const size_t gredF = (size_t)BH * DK * DK;      // 1M floats (4 MB)
  const size_t need8 = ((size_t)BH * 8 * 32768 + gredF) * sizeof(float);  // ~71 MB

  hipMemcpyAsync(newZ, zg, sizeof(float) * (size_t)BH * DK,
                 hipMemcpyDeviceToDevice, stream);

  if (ws_size >= need8) {
    float* Pp   = (float*)d_ws;
    float* Gred = Pp + (size_t)BH * 8 * 32768;
    delta_phase1<8, true><<<dim3(8, BH), 512, 0, stream>>>(Kg, Vg, Pp, nullptr, newZ);
    delta_reduce<<<dim3(8, BH), 256, 0, stream>>>(Pp, Mg, newM, Gred, 8);
    delta_gm<<<dim3(8, BH), 256, 0, stream>>>(Mg, Gred, newM);
  } else {
    // Atomic fallback: newM/Gws pre-initialized, phase1 accumulates in place.
    float* Gws = (float*)d_ws;                    // 4 MB
    hipMemcpyAsync(newM, Mg, sizeof(float) * (size_t)BH * DK * DV,
                   hipMemcpyDeviceToDevice, stream);
    hipMemsetAsync(Gws, 0, sizeof(float) * gredF, stream);
    delta_phase1<8, false><<<dim3(8, BH), 512, 0, stream>>>(Kg, Vg, newM, Gws, newZ);
    delta_gm<<<dim3(8, BH), 256, 0, stream>>>(Mg, Gws, newM);
  }
}